// Round 9
// baseline (203.284 us; speedup 1.0000x reference)
//
#include <hip/hip_runtime.h>

#define N_NODES 100000
#define N_EDGES 1600000
#define NUM_HEADS 4
#define NEG_SLOPE 0.2f
#define LDSTRIDE 136   // 16-bit elems: 272 B rows (68 dwords ≡ 4 mod 32 banks)
#define GEMM_BLOCKS 782   // ceil(100000/128)
#define SEG_BLOCKS 1563   // ceil(400000/256) threads, 4 edges each

typedef __attribute__((ext_vector_type(8))) short bf16x8;
typedef __attribute__((ext_vector_type(4))) float f32x4;

__device__ __forceinline__ unsigned short f2bf(float x) {
    union { float f; unsigned u; } v; v.f = x;
    unsigned r = v.u + 0x7fffu + ((v.u >> 16) & 1u);   // RN-even
    return (unsigned short)(r >> 16);
}
__device__ __forceinline__ unsigned short f2h(float x) {
    union { _Float16 h; unsigned short u; } v; v.h = (_Float16)x;  // v_cvt_f16_f32 RNE
    return v.u;
}

// ---------------------------------------------------------------------------
// Kernel 1: gemm + seg, TWO-DISPATCH pipeline (prep_kernel eliminated).
// Each gemm block builds B_lds DIRECTLY from W/attn (no global Wt2, no
// prep dispatch, no inter-dispatch dependency):
//   rows 0..127 : B_lds[n][k] = bf16(W[k][n])  (transpose+convert; reads
//                 coalesced over n per fixed k, 8B ushort4 LDS writes)
//   rows 128..135: wl/wr dot rows, same sequential 32-FMA order as the old
//                 prep kernel -> ft/el/er BIT-IDENTICAL to round 8.
// Cost: ~64 KB L2-hot W reads + ~1K dots per block (~1-2 us total phase).
// Blocks [GEMM_BLOCKS, +SEG_BLOCKS): seg[] from sorted dst (unchanged).
// This tests the per-dispatch-overhead hypothesis: 3 dispatches -> 2.
// ---------------------------------------------------------------------------
__global__ __launch_bounds__(256, 3) void gemm_seg_kernel(
    const float* __restrict__ feat, const float* __restrict__ W,
    const float* __restrict__ attn_l, const float* __restrict__ attn_r,
    unsigned short* __restrict__ ft, float* __restrict__ el,
    float* __restrict__ er, const int* __restrict__ dst,
    int* __restrict__ seg)
{
    __shared__ __align__(16) unsigned short B_lds[136 * LDSTRIDE];  // 36992 B

    if (blockIdx.x >= GEMM_BLOCKS) {
        // ---- seg part (block-uniform branch; no barriers on this path) ----
        int i4 = (int)(blockIdx.x - GEMM_BLOCKS) * 256 + threadIdx.x;
        if (i4 >= N_EDGES / 4) return;
        const int e0 = 4 * i4;
        const int4 d = ((const int4*)dst)[i4];
        const int dp = (e0 == 0) ? -1 : dst[e0 - 1];
        for (int n = dp + 1; n <= d.x; ++n) seg[n] = e0;
        for (int n = d.x + 1; n <= d.y; ++n) seg[n] = e0 + 1;
        for (int n = d.y + 1; n <= d.z; ++n) seg[n] = e0 + 2;
        for (int n = d.z + 1; n <= d.w; ++n) seg[n] = e0 + 3;
        if (e0 + 4 == N_EDGES)
            for (int n = d.w + 1; n <= N_NODES; ++n) seg[n] = N_EDGES;
        return;
    }

    // ---- gemm part ----
    const int t = threadIdx.x;
    const int nbase = blockIdx.x * 128;
    const int w = t >> 6, lane = t & 63;
    const int l15 = lane & 15, quad = lane >> 4;

    // issue feat loads FIRST (in flight during B_lds build)
    int g0 = nbase + w * 32 + l15;      if (g0 >= N_NODES) g0 = N_NODES - 1;
    int g1 = nbase + w * 32 + 16 + l15; if (g1 >= N_NODES) g1 = N_NODES - 1;
    const float4* f40 = (const float4*)feat + (size_t)g0 * 32 + quad * 2;
    const float4* f41 = (const float4*)feat + (size_t)g1 * 32 + quad * 2;
    float4 fr0[8], fr1[8];
#pragma unroll
    for (int ks = 0; ks < 4; ++ks) {
        fr0[2 * ks] = f40[ks * 8]; fr0[2 * ks + 1] = f40[ks * 8 + 1];
        fr1[2 * ks] = f41[ks * 8]; fr1[2 * ks + 1] = f41[ks * 8 + 1];
    }

    {   // (a) transpose W -> B_lds rows 0..127: thread = (n, kg of 4 k's)
        // reads coalesced over n (lanes sweep n for fixed k); ushort4 write
#pragma unroll
        for (int i = 0; i < 16; ++i) {
            int idx = t + 256 * i;            // [0,4096)
            int n = idx & 127, kg = idx >> 7; // kg in [0,32)
            ushort4 u;
            u.x = f2bf(W[(4 * kg + 0) * 128 + n]);
            u.y = f2bf(W[(4 * kg + 1) * 128 + n]);
            u.z = f2bf(W[(4 * kg + 2) * 128 + n]);
            u.w = f2bf(W[(4 * kg + 3) * 128 + n]);
            *(ushort4*)(&B_lds[n * LDSTRIDE + 4 * kg]) = u;
        }
    }
    {   // (b) wl/wr rows 128..135 (same per-entry sequential dot as old prep)
#pragma unroll
        for (int i = 0; i < 4; ++i) {
            int idx = t + 256 * i;            // [0,1024)
            int r = idx >> 7, k = idx & 127;  // r in [0,8)
            int h = r & 3;
            const float* av = (r < 4 ? attn_l : attn_r) + h * 32;
            const float* col = W + k * 128 + h * 32;
            float s = 0.f;
#pragma unroll
            for (int d2 = 0; d2 < 32; ++d2) s += col[d2] * av[d2];
            B_lds[(128 + r) * LDSTRIDE + k] = f2bf(s);
        }
    }
    __syncthreads();

    bf16x8 a0[4], a1[4];
#pragma unroll
    for (int ks = 0; ks < 4; ++ks) {
        float4 fa = fr0[2 * ks], fb = fr0[2 * ks + 1];
        a0[ks][0] = (short)f2bf(fa.x); a0[ks][1] = (short)f2bf(fa.y);
        a0[ks][2] = (short)f2bf(fa.z); a0[ks][3] = (short)f2bf(fa.w);
        a0[ks][4] = (short)f2bf(fb.x); a0[ks][5] = (short)f2bf(fb.y);
        a0[ks][6] = (short)f2bf(fb.z); a0[ks][7] = (short)f2bf(fb.w);
        fa = fr1[2 * ks]; fb = fr1[2 * ks + 1];
        a1[ks][0] = (short)f2bf(fa.x); a1[ks][1] = (short)f2bf(fa.y);
        a1[ks][2] = (short)f2bf(fa.z); a1[ks][3] = (short)f2bf(fa.w);
        a1[ks][4] = (short)f2bf(fb.x); a1[ks][5] = (short)f2bf(fb.y);
        a1[ks][6] = (short)f2bf(fb.z); a1[ks][7] = (short)f2bf(fb.w);
    }

    f32x4 acc0[9], acc1[9];
#pragma unroll
    for (int c = 0; c < 9; ++c) {
        acc0[c] = (f32x4){0.f, 0.f, 0.f, 0.f};
        acc1[c] = (f32x4){0.f, 0.f, 0.f, 0.f};
    }

    const unsigned short* Brow = &B_lds[l15 * LDSTRIDE + quad * 8];
    const unsigned short* Brow8 = &B_lds[(128 + (l15 & 7)) * LDSTRIDE + quad * 8];
#pragma unroll
    for (int ks = 0; ks < 4; ++ks) {
#pragma unroll
        for (int c = 0; c < 8; ++c) {
            bf16x8 b = *(const bf16x8*)(Brow + (c * 16) * LDSTRIDE + ks * 32);
            acc0[c] = __builtin_amdgcn_mfma_f32_16x16x32_bf16(a0[ks], b, acc0[c], 0, 0, 0);
            acc1[c] = __builtin_amdgcn_mfma_f32_16x16x32_bf16(a1[ks], b, acc1[c], 0, 0, 0);
        }
        bf16x8 b8 = *(const bf16x8*)(Brow8 + ks * 32);
        acc0[8] = __builtin_amdgcn_mfma_f32_16x16x32_bf16(a0[ks], b8, acc0[8], 0, 0, 0);
        acc1[8] = __builtin_amdgcn_mfma_f32_16x16x32_bf16(a1[ks], b8, acc1[8], 0, 0, 0);
    }

    // el/er from acc[8], both tiles: col l15<4 -> el head l15; [4,8) -> er
#pragma unroll
    for (int reg = 0; reg < 4; ++reg) {
        const int ga = nbase + w * 32 + quad * 4 + reg;
        if (ga < N_NODES) {
            if (l15 < 4)      el[ga * 4 + l15] = acc0[8][reg];
            else if (l15 < 8) er[ga * 4 + (l15 - 4)] = acc0[8][reg];
        }
        const int gb = ga + 16;
        if (gb < N_NODES) {
            if (l15 < 4)      el[gb * 4 + l15] = acc1[8][reg];
            else if (l15 < 8) er[gb * 4 + (l15 - 4)] = acc1[8][reg];
        }
    }

    __syncthreads();   // everyone done reading B_lds -> reuse as ft scratch
#pragma unroll
    for (int c = 0; c < 8; ++c) {
#pragma unroll
        for (int reg = 0; reg < 4; ++reg) {
            B_lds[(w * 32 + quad * 4 + reg) * LDSTRIDE + c * 16 + l15] =
                f2h(acc0[c][reg]);                      // FP16 pack, tile 0
            B_lds[(w * 32 + 16 + quad * 4 + reg) * LDSTRIDE + c * 16 + l15] =
                f2h(acc1[c][reg]);                      // FP16 pack, tile 1
        }
    }
    __syncthreads();

    // coalesced repack: 128 rows x 128 cols fp16 -> global int4
#pragma unroll
    for (int i = 0; i < 8; ++i) {
        int idx = t + 256 * i;                // [0,2048)
        int node = idx >> 4, cg = idx & 15;
        int gg = nbase + node;
        if (gg < N_NODES) {
            int4 val = *(const int4*)(&B_lds[node * LDSTRIDE + cg * 8]);
            *(int4*)(&ft[(size_t)gg * 128 + cg * 8]) = val;
        }
    }
}

// ---------------------------------------------------------------------------
// Kernel 2: aggregation — BYTE-IDENTICAL to round 8 (floor core + NT out
// stores). At the random-gather fill ceiling: ~282 MB @ ~3.8 TB/s; seven
// structural variants within 73.4-79.0 us; NT stores cut FETCH 2% with no
// time change (fill-path-limited, not byte-limited).
// ---------------------------------------------------------------------------
__global__ __launch_bounds__(256) void aggregate_kernel(
    const unsigned short* __restrict__ ft, const float* __restrict__ el,
    const float* __restrict__ er, const int* __restrict__ src,
    const int* __restrict__ seg, float* __restrict__ out)
{
    const int node = blockIdx.x * 4 + (threadIdx.x >> 6);
    if (node >= N_NODES) return;
    const int lane = threadIdx.x & 63;
    const int qt = lane >> 4;         // quarter: edges c0+4qt .. +3
    const int l15 = lane & 15;        // feature group: feats 8*l15..+7
    const int hf = l15 >> 2;          // head of this lane's features/scores

    const int beg = __builtin_amdgcn_readfirstlane(seg[node]);
    const int end = __builtin_amdgcn_readfirstlane(seg[node + 1]);
    const float er_h = er[node * 4 + hf];

    float dpart = 0.f;
    float4 accA = make_float4(0.f, 0.f, 0.f, 0.f);
    float4 accB = make_float4(0.f, 0.f, 0.f, 0.f);

    for (int c0 = beg; c0 < end; c0 += 16) {
        const int cb = c0 + 4 * qt;
        int s4[4];
#pragma unroll
        for (int k = 0; k < 4; ++k) {
            int ci = cb + k;
            s4[k] = src[ci < end ? ci : end - 1];   // clamp (p forced 0)
        }
        float ev[4];
#pragma unroll
        for (int k = 0; k < 4; ++k) ev[k] = el[s4[k] * 4 + hf];
        float p[4];
#pragma unroll
        for (int k = 0; k < 4; ++k) {
            float e = ev[k] + er_h;
            e = (e > 0.f) ? e : NEG_SLOPE * e;
            p[k] = (cb + k < end) ? __expf(e) : 0.f;
            dpart += p[k];
        }
        uint4 v[4];
#pragma unroll
        for (int k = 0; k < 4; ++k)
            v[k] = *(const uint4*)(ft + (((size_t)(unsigned)s4[k]) << 7) + l15 * 8);
#pragma unroll
        for (int k = 0; k < 4; ++k) {
            const float pj = p[k];
            // acc += (float)f16half(v) * pj, one instruction per element
            asm("v_fma_mix_f32 %0, %2, %3, %0 op_sel_hi:[1,0,0]\n\t"
                "v_fma_mix_f32 %1, %2, %3, %1 op_sel:[1,0,0] op_sel_hi:[1,0,0]"
                : "+v"(accA.x), "+v"(accA.y) : "v"(v[k].x), "v"(pj));
            asm("v_fma_mix_f32 %0, %2, %3, %0 op_sel_hi:[1,0,0]\n\t"
                "v_fma_mix_f32 %1, %2, %3, %1 op_sel:[1,0,0] op_sel_hi:[1,0,0]"
                : "+v"(accA.z), "+v"(accA.w) : "v"(v[k].y), "v"(pj));
            asm("v_fma_mix_f32 %0, %2, %3, %0 op_sel_hi:[1,0,0]\n\t"
                "v_fma_mix_f32 %1, %2, %3, %1 op_sel:[1,0,0] op_sel_hi:[1,0,0]"
                : "+v"(accB.x), "+v"(accB.y) : "v"(v[k].z), "v"(pj));
            asm("v_fma_mix_f32 %0, %2, %3, %0 op_sel_hi:[1,0,0]\n\t"
                "v_fma_mix_f32 %1, %2, %3, %1 op_sel:[1,0,0] op_sel_hi:[1,0,0]"
                : "+v"(accB.z), "+v"(accB.w) : "v"(v[k].w), "v"(pj));
        }
    }

    // reduce across quarters (lanes ^16, ^32); dpart rides along
    dpart  += __shfl_xor(dpart, 16);
    accA.x += __shfl_xor(accA.x, 16); accA.y += __shfl_xor(accA.y, 16);
    accA.z += __shfl_xor(accA.z, 16); accA.w += __shfl_xor(accA.w, 16);
    accB.x += __shfl_xor(accB.x, 16); accB.y += __shfl_xor(accB.y, 16);
    accB.z += __shfl_xor(accB.z, 16); accB.w += __shfl_xor(accB.w, 16);
    dpart  += __shfl_xor(dpart, 32);
    accA.x += __shfl_xor(accA.x, 32); accA.y += __shfl_xor(accA.y, 32);
    accA.z += __shfl_xor(accA.z, 32); accA.w += __shfl_xor(accA.w, 32);
    accB.x += __shfl_xor(accB.x, 32); accB.y += __shfl_xor(accB.y, 32);
    accB.z += __shfl_xor(accB.z, 32); accB.w += __shfl_xor(accB.w, 32);

    const float inv = (dpart > 0.f) ? 1.f / dpart : 0.f; // degree-0 -> zeros

    if (qt == 0) {
        f32x4 o0 = {accA.x * inv, accA.y * inv, accA.z * inv, accA.w * inv};
        f32x4 o1 = {accB.x * inv, accB.y * inv, accB.z * inv, accB.w * inv};
        float* op = out + (size_t)node * 128 + l15 * 8;
        __builtin_nontemporal_store(o0, (f32x4*)op);         // write-only out:
        __builtin_nontemporal_store(o1, (f32x4*)(op + 4));   // don't evict ft
    }
}

// ---------------------------------------------------------------------------
extern "C" void kernel_launch(void* const* d_in, const int* in_sizes, int n_in,
                              void* d_out, int out_size, void* d_ws, size_t ws_size,
                              hipStream_t stream) {
    const float* feat   = (const float*)d_in[0];
    const int*   src    = (const int*)d_in[1];
    const int*   dst    = (const int*)d_in[2];
    const float* W      = (const float*)d_in[3];
    const float* attn_l = (const float*)d_in[4];
    const float* attn_r = (const float*)d_in[5];
    float* out = (float*)d_out;

    unsigned short* ft = (unsigned short*)d_ws;               // 12.8M fp16
    float* el  = (float*)(ft + (size_t)12800000);
    float* er  = el + 400000;
    int* seg = (int*)(er + 400000);                           // 100001 int

    gemm_seg_kernel<<<GEMM_BLOCKS + SEG_BLOCKS, 256, 0, stream>>>(
        feat, W, attn_l, attn_r, ft, el, er, dst, seg);
    aggregate_kernel<<<(N_NODES + 3) / 4, 256, 0, stream>>>(
        ft, el, er, src, seg, out);
}